// Round 9
// baseline (341.843 us; speedup 1.0000x reference)
//
#include <hip/hip_runtime.h>

// Problem constants
constexpr int Hd = 512;
constexpr int Bd = 64;
constexpr int Sd = 2048;

constexpr int BM = 128;   // o-rows per block (2 waves)
constexpr int BN = 64;    // s-cols per block (2 waves); full K staged once

typedef __bf16 bf16x8 __attribute__((ext_vector_type(8)));
typedef float  f32x4  __attribute__((ext_vector_type(4)));
typedef unsigned short u16x8 __attribute__((ext_vector_type(8)));

__device__ __forceinline__ unsigned short f2bf(float f){
  __bf16 h = (__bf16)f;
  return __builtin_bit_cast(unsigned short, h);
}

__device__ __forceinline__ float fast_tanh(float x){
  float e = __expf(2.0f * x);
  return 1.0f - 2.0f * __builtin_amdgcn_rcpf(e + 1.0f);
}

__device__ __forceinline__ u16x8 cvt8u(f32x4 lo, f32x4 hi){
  u16x8 r;
  r[0]=f2bf(lo[0]); r[1]=f2bf(lo[1]); r[2]=f2bf(lo[2]); r[3]=f2bf(lo[3]);
  r[4]=f2bf(hi[0]); r[5]=f2bf(hi[1]); r[6]=f2bf(hi[2]); r[7]=f2bf(hi[3]);
  return r;
}

// Prologue: blocks [0,128) convert Wr f32->bf16 row-major; blocks [128,192) qproj
__global__ __launch_bounds__(256) void prologue_kernel(const float* __restrict__ Wr,
                                                       unsigned short* __restrict__ Wrb,
                                                       const float* __restrict__ query,
                                                       const float* __restrict__ Wq,
                                                       const float* __restrict__ bq,
                                                       float* __restrict__ qout){
  if (blockIdx.x < 128){
    int base = (blockIdx.x*256 + (int)threadIdx.x) * 8;
    f32x4 v0 = *(const f32x4*)(Wr + base);
    f32x4 v1 = *(const f32x4*)(Wr + base + 4);
    *(u16x8*)(Wrb + base) = cvt8u(v0, v1);
  } else {
    int b   = blockIdx.x - 128;
    int tid = threadIdx.x;
    __shared__ float qs[Hd];
    for (int i = tid; i < Hd; i += 256) qs[i] = query[b*Hd + i];
    __syncthreads();
    for (int o = tid; o < Hd; o += 256){
      const float* w = Wq + (size_t)o*Hd;
      float s = 0.f;
      #pragma unroll 4
      for (int k = 0; k < Hd; k += 4){
        f32x4 wv = *(const f32x4*)(w + k);
        s += wv[0]*qs[k] + wv[1]*qs[k+1] + wv[2]*qs[k+2] + wv[3]*qs[k+3];
      }
      qout[b*Hd + o] = s + bq[o];
    }
  }
}

// Per batch b: C[o][s] = sum_h Wr[o][h] * ref[b][s][h]; fused tanh/V logits.
// Structure: stage B (64 s-rows x full K=512, bf16, XOR-swizzled) ONCE ->
// one __syncthreads -> barrier-free fully-unrolled 16-step MFMA loop
// (A-frags direct from L2-hot Wrb, dist-2; B-frags ds_read_b128, dist-2).
__global__ __launch_bounds__(256) void fused_kernel(const float* __restrict__ ref,
                                                    const unsigned short* __restrict__ Wrb,
                                                    const float* __restrict__ br,
                                                    const float* __restrict__ V,
                                                    const float* __restrict__ qbuf,
                                                    float* __restrict__ out,     // [B][H][S]
                                                    float* __restrict__ logits){ // [B][S]
  // Bijective XCD swizzle (nwg=8192 divisible by 8): 4 mt-blocks sharing a ref
  // panel land consecutively on the SAME XCD (their L2 merges the HBM fetch).
  const int bid = blockIdx.x;
  const int wid = (bid & 7) * (gridDim.x >> 3) + (bid >> 3);
  const int mt  = wid & 3;          // 4 m-tiles of 128
  const int nt  = (wid >> 2) & 31;  // 32 n-tiles of 64
  const int bb  = wid >> 7;
  const int m0  = mt * BM;
  const int n0  = nt * BN;

  const int tid  = threadIdx.x;
  const int lane = tid & 63;
  const int wave = tid >> 6;
  const int wm   = wave >> 1;   // 2x2 wave grid: wave owns 64 o x 32 s
  const int wn   = wave & 1;

  // 64 rows x 512 bf16 = 64 KB. Row = 64 slots of 16B; phys slot XOR-swizzled
  // within 8-slot groups so 16-rows-same-slot frag reads spread over all banks.
  __shared__ unsigned short Bls[BN * Hd];

  // ---------------- stage: full-K B tile, one pass, depth-4 pipelined ----------------
  {
    const float* srow = ref + ((size_t)bb*Sd + n0 + wave*16)*Hd + lane*8;
    f32x4 va[4], vb[4];
    #pragma unroll
    for (int u = 0; u < 4; ++u){
      va[u] = *(const f32x4*)(srow + (size_t)u*Hd);
      vb[u] = *(const f32x4*)(srow + (size_t)u*Hd + 4);
    }
    #pragma unroll
    for (int u = 0; u < 16; ++u){
      const int s = u & 3;
      u16x8 o = cvt8u(va[s], vb[s]);
      if (u + 4 < 16){
        va[s] = *(const f32x4*)(srow + (size_t)(u+4)*Hd);
        vb[s] = *(const f32x4*)(srow + (size_t)(u+4)*Hd + 4);
      }
      const int row = wave*16 + u;
      const int ps  = (lane & ~7) | ((lane & 7) ^ (row & 7));   // slot = lane
      *(u16x8*)(&Bls[row*Hd + ps*8]) = o;
    }
  }

  // A-frag geometry (direct global, L2-hot Wrb): lane row = l&15, k = (l>>4)*8 + j
  const int r16 = lane & 15;
  const int kg8 = (lane >> 4) * 8;
  const unsigned short* Abase = Wrb + (size_t)(m0 + wm*64 + r16)*Hd + kg8;

  f32x4 acc[4][2];
  #pragma unroll
  for (int i = 0; i < 4; ++i)
    #pragma unroll
    for (int j = 0; j < 2; ++j)
      acc[i][j] = f32x4{0.f, 0.f, 0.f, 0.f};

  bf16x8 Aq[2][4], Bq[2][2];

  auto loadA = [&](bf16x8 (&A)[4], int t){
    #pragma unroll
    for (int mi = 0; mi < 4; ++mi)
      A[mi] = *(const bf16x8*)(Abase + (size_t)mi*16*Hd + t*32);
  };
  auto loadB = [&](bf16x8 (&B)[2], int t){
    #pragma unroll
    for (int ni = 0; ni < 2; ++ni){
      const int r    = wn*32 + ni*16 + r16;
      const int slot = t*4 + (lane >> 4);
      const int ps   = (slot & ~7) | ((slot & 7) ^ (r & 7));
      B[ni] = *(const bf16x8*)(&Bls[r*Hd + ps*8]);
    }
  };

  loadA(Aq[0], 0);          // A preloads overlap the stage drain
  loadA(Aq[1], 1);
  __syncthreads();          // the ONLY block-wide barrier
  loadB(Bq[0], 0);
  loadB(Bq[1], 1);

  // ---------------- compute: 16 steps, no barriers, dist-2 reg pipeline ----------------
  #pragma unroll
  for (int t = 0; t < 16; ++t){
    const int p = t & 1;    // static under full unroll
    #pragma unroll
    for (int ni = 0; ni < 2; ++ni)
      #pragma unroll
      for (int mi = 0; mi < 4; ++mi)
        acc[mi][ni] = __builtin_amdgcn_mfma_f32_16x16x32_bf16(Aq[p][mi], Bq[p][ni], acc[mi][ni], 0, 0, 0);
    if (t < 14){
      loadA(Aq[p], t + 2);
      loadB(Bq[p], t + 2);
    }
  }

  // ---- epilogue: +br, NT-store ref_t, fused tanh/V column sums ----
  const int col0 = n0 + wn*32;
  const int row0 = m0 + wm*64;
  const int cl   = lane & 15;          // C/D: col = lane&15
  const int rgrp = (lane >> 4) * 4;    //      row = (lane>>4)*4 + j
  const float* qrow = qbuf + bb*Hd;
  float colsum[2] = {0.f, 0.f};
  float* outb = out + (size_t)bb*Hd*Sd;

  #pragma unroll
  for (int mi = 0; mi < 4; ++mi){
    #pragma unroll
    for (int j = 0; j < 4; ++j){
      int o = row0 + mi*16 + rgrp + j;
      float brv = br[o];
      float qv  = qrow[o];
      float vv  = V[o];
      float* orow = outb + (size_t)o*Sd + col0;
      #pragma unroll
      for (int ni = 0; ni < 2; ++ni){
        float c = acc[mi][ni][j] + brv;
        __builtin_nontemporal_store(c, &orow[ni*16 + cl]);  // don't thrash L2/L3
        colsum[ni] += vv * fast_tanh(qv + c);
      }
    }
  }

  // reduce over the wave's 64 rows: lanes sharing (lane&15) are l, l^16, l^32, l^48
  #pragma unroll
  for (int ni = 0; ni < 2; ++ni){
    colsum[ni] += __shfl_xor(colsum[ni], 16);
    colsum[ni] += __shfl_xor(colsum[ni], 32);
  }
  if (lane < 16){
    float* lrow = logits + (size_t)bb*Sd + col0;
    #pragma unroll
    for (int ni = 0; ni < 2; ++ni)
      atomicAdd(lrow + ni*16 + cl, colsum[ni]);
  }
}

extern "C" void kernel_launch(void* const* d_in, const int* in_sizes, int n_in,
                              void* d_out, int out_size, void* d_ws, size_t ws_size,
                              hipStream_t stream){
  const float* query = (const float*)d_in[0];
  const float* ref   = (const float*)d_in[1];
  const float* Wq    = (const float*)d_in[2];
  const float* bq    = (const float*)d_in[3];
  const float* Wr    = (const float*)d_in[4];
  const float* br    = (const float*)d_in[5];
  const float* V     = (const float*)d_in[6];

  float* out    = (float*)d_out;
  float* logits = out + (size_t)Bd*Hd*Sd;   // second output, concatenated flat
  float* qbuf   = (float*)d_ws;                                      // [B][H] f32 = 128 KB
  unsigned short* Wrb = (unsigned short*)((char*)d_ws + 128*1024);   // [H][H] bf16 = 512 KB

  hipMemsetAsync(logits, 0, (size_t)Bd*Sd*sizeof(float), stream);
  prologue_kernel<<<192, 256, 0, stream>>>(Wr, Wrb, query, Wq, bq, qbuf);

  // grid: 64 batches x (32 n-tiles x 4 m-tiles), XCD-swizzled in-kernel
  fused_kernel<<<Bd*4*32, 256, 0, stream>>>(ref, Wrb, br, V, qbuf, out, logits);
}

// Round 10
// 213.599 us; speedup vs baseline: 1.6004x; 1.6004x over previous
//
#include <hip/hip_runtime.h>

// Problem constants
constexpr int Hd = 512;
constexpr int Bd = 64;
constexpr int Sd = 2048;

constexpr int BM = 128;
constexpr int BN = 128;
constexpr int BK = 32;
constexpr int LDP = BK + 4;   // 72B row stride (proven r2): modest conflicts, 8B-aligned b128

typedef __bf16 bf16x8 __attribute__((ext_vector_type(8)));
typedef float  f32x4  __attribute__((ext_vector_type(4)));
typedef unsigned short u16x8 __attribute__((ext_vector_type(8)));

__device__ __forceinline__ unsigned short f2bf(float f){
  __bf16 h = (__bf16)f;
  return __builtin_bit_cast(unsigned short, h);
}

// insert-of-fptrunc form: lets the compiler select v_cvt_pk_bf16_f32 pairs
__device__ __forceinline__ u16x8 cvt8u(f32x4 lo, f32x4 hi){
  u16x8 r;
  r[0]=f2bf(lo[0]); r[1]=f2bf(lo[1]); r[2]=f2bf(lo[2]); r[3]=f2bf(lo[3]);
  r[4]=f2bf(hi[0]); r[5]=f2bf(hi[1]); r[6]=f2bf(hi[2]); r[7]=f2bf(hi[3]);
  return r;
}

__device__ __forceinline__ float fast_tanh(float x){
  float e = __expf(2.0f * x);
  return 1.0f - 2.0f * __builtin_amdgcn_rcpf(e + 1.0f);
}

// Prologue: blocks [0,128) convert Wr f32->bf16 row-major; blocks [128,192) qproj
__global__ __launch_bounds__(256) void prologue_kernel(const float* __restrict__ Wr,
                                                       unsigned short* __restrict__ Wrb,
                                                       const float* __restrict__ query,
                                                       const float* __restrict__ Wq,
                                                       const float* __restrict__ bq,
                                                       float* __restrict__ qout){
  if (blockIdx.x < 128){
    int base = (blockIdx.x*256 + (int)threadIdx.x) * 8;
    f32x4 v0 = *(const f32x4*)(Wr + base);
    f32x4 v1 = *(const f32x4*)(Wr + base + 4);
    *(u16x8*)(Wrb + base) = cvt8u(v0, v1);
  } else {
    int b   = blockIdx.x - 128;
    int tid = threadIdx.x;
    __shared__ float qs[Hd];
    for (int i = tid; i < Hd; i += 256) qs[i] = query[b*Hd + i];
    __syncthreads();
    for (int o = tid; o < Hd; o += 256){
      const float* w = Wq + (size_t)o*Hd;
      float s = 0.f;
      #pragma unroll 4
      for (int k = 0; k < Hd; k += 4){
        f32x4 wv = *(const f32x4*)(w + k);
        s += wv[0]*qs[k] + wv[1]*qs[k+1] + wv[2]*qs[k+2] + wv[3]*qs[k+3];
      }
      qout[b*Hd + o] = s + bq[o];
    }
  }
}

struct SReg { u16x8 a0, a1; f32x4 b[4]; };

// Per batch b: C[o][s] = sum_h Wr[o][h] * ref[b][s][h]; fused tanh/V logits.
// r2's proven 2-barrier two-reg-set dist-1 skeleton; A from bf16 Wrb;
// B staged as 1 row x 16 consecutive f32 per thread (coalesced 64B runs).
__global__ __launch_bounds__(256, 3) void fused_kernel(const float* __restrict__ ref,
                                                       const unsigned short* __restrict__ Wrb,
                                                       const float* __restrict__ br,
                                                       const float* __restrict__ V,
                                                       const float* __restrict__ qbuf,
                                                       float* __restrict__ out,     // [B][H][S]
                                                       float* __restrict__ logits){ // [B][S]
  // Bijective XCD swizzle (nwg=4096 divisible by 8): 4 mt-blocks sharing a ref
  // panel land consecutively on the SAME XCD -> panel fetched from HBM once.
  const int bid = blockIdx.x;
  const int wid = (bid & 7) * (gridDim.x >> 3) + (bid >> 3);
  const int mt  = wid & 3;
  const int nt  = (wid >> 2) & 15;
  const int bb  = wid >> 6;
  const int m0  = mt * BM;
  const int n0  = nt * BN;

  const int tid  = threadIdx.x;
  const int lane = tid & 63;
  const int wave = tid >> 6;
  const int wm   = wave >> 1;   // 2x2 wave grid, each wave owns 64x64 of C
  const int wn   = wave & 1;

  __shared__ unsigned short As[BM][LDP];
  __shared__ unsigned short Bs[BN][LDP];

  f32x4 acc[4][4];
  #pragma unroll
  for (int i = 0; i < 4; ++i)
    #pragma unroll
    for (int j = 0; j < 4; ++j)
      acc[i][j] = f32x4{0.f, 0.f, 0.f, 0.f};

  // A staging (bf16 source): thread = row ar, 16 bf16 at ak (2 b128 ld/st)
  const int ar = tid >> 1;
  const int ak = (tid & 1) * 16;
  // B staging (f32 source): thread = row sr, 16 CONSECUTIVE f32 at sk (64B run)
  const int sr = tid >> 1;
  const int sk = (tid & 1) * 16;

  const unsigned short* Ag = Wrb + (size_t)(m0 + ar)*Hd + ak;
  const float*          Bg = ref + ((size_t)bb*Sd + (n0 + sr))*Hd + sk;

  const int rofs = lane & 15;
  const int koff = (lane >> 4) * 8;

  SReg S0, S1;

  auto issue = [&](SReg& S, int kt){
    S.a0 = *(const u16x8*)(Ag + kt);
    S.a1 = *(const u16x8*)(Ag + kt + 8);
    #pragma unroll
    for (int it = 0; it < 4; ++it) S.b[it] = *(const f32x4*)(Bg + kt + it*4);
  };
  auto write_stage = [&](const SReg& S){
    *(u16x8*)(&As[ar][ak])     = S.a0;
    *(u16x8*)(&As[ar][ak + 8]) = S.a1;
    *(u16x8*)(&Bs[sr][sk])     = cvt8u(S.b[0], S.b[1]);
    *(u16x8*)(&Bs[sr][sk + 8]) = cvt8u(S.b[2], S.b[3]);
  };
  // halfstep t: stage tile t (regs issued at t-1 into the OTHER set), issue t+1
  auto step = [&](const SReg& Sw, SReg& Sn, int t){
    write_stage(Sw);
    int kn = t + 1; kn = (kn > 15 ? 15 : kn) * BK;
    issue(Sn, kn);                            // in flight across the barrier pair
    asm volatile("s_waitcnt lgkmcnt(0)" ::: "memory");
    __builtin_amdgcn_s_barrier();
    bf16x8 a[4], b[4];
    #pragma unroll
    for (int mi = 0; mi < 4; ++mi)
      a[mi] = *(const bf16x8*)(&As[wm*64 + mi*16 + rofs][koff]);
    #pragma unroll
    for (int ni = 0; ni < 4; ++ni)
      b[ni] = *(const bf16x8*)(&Bs[wn*64 + ni*16 + rofs][koff]);
    #pragma unroll
    for (int mi = 0; mi < 4; ++mi)
      #pragma unroll
      for (int ni = 0; ni < 4; ++ni)
        acc[mi][ni] = __builtin_amdgcn_mfma_f32_16x16x32_bf16(a[mi], b[ni], acc[mi][ni], 0, 0, 0);
    asm volatile("s_waitcnt lgkmcnt(0)" ::: "memory");  // frag reads done before next writes
    __builtin_amdgcn_s_barrier();
  };

  issue(S0, 0);
  #pragma unroll 1
  for (int t2 = 0; t2 < 8; ++t2){
    step(S0, S1, t2*2);
    step(S1, S0, t2*2 + 1);
  }

  // ---- epilogue: +br, NT-store ref_t, fused tanh/V column sums ----
  const int col0 = n0 + wn*64;
  const int row0 = m0 + wm*64;
  const int cl   = lane & 15;          // C/D: col = lane&15
  const int rgrp = (lane >> 4) * 4;    //      row = (lane>>4)*4 + j
  const float* qrow = qbuf + bb*Hd;
  float colsum[4] = {0.f, 0.f, 0.f, 0.f};
  float* outb = out + (size_t)bb*Hd*Sd;

  #pragma unroll
  for (int mi = 0; mi < 4; ++mi){
    #pragma unroll
    for (int j = 0; j < 4; ++j){
      int o = row0 + mi*16 + rgrp + j;
      float brv = br[o];
      float qv  = qrow[o];
      float vv  = V[o];
      float* orow = outb + (size_t)o*Sd + col0;
      #pragma unroll
      for (int ni = 0; ni < 4; ++ni){
        float c = acc[mi][ni][j] + brv;
        __builtin_nontemporal_store(c, &orow[ni*16 + cl]);  // don't thrash L2/L3
        colsum[ni] += vv * fast_tanh(qv + c);
      }
    }
  }

  // reduce over the wave's 64 rows: lanes sharing (lane&15) are l, l^16, l^32, l^48
  #pragma unroll
  for (int ni = 0; ni < 4; ++ni){
    colsum[ni] += __shfl_xor(colsum[ni], 16);
    colsum[ni] += __shfl_xor(colsum[ni], 32);
  }
  if (lane < 16){
    float* lrow = logits + (size_t)bb*Sd + col0;
    #pragma unroll
    for (int ni = 0; ni < 4; ++ni)
      atomicAdd(lrow + ni*16 + cl, colsum[ni]);
  }
}

extern "C" void kernel_launch(void* const* d_in, const int* in_sizes, int n_in,
                              void* d_out, int out_size, void* d_ws, size_t ws_size,
                              hipStream_t stream){
  const float* query = (const float*)d_in[0];
  const float* ref   = (const float*)d_in[1];
  const float* Wq    = (const float*)d_in[2];
  const float* bq    = (const float*)d_in[3];
  const float* Wr    = (const float*)d_in[4];
  const float* br    = (const float*)d_in[5];
  const float* V     = (const float*)d_in[6];

  float* out    = (float*)d_out;
  float* logits = out + (size_t)Bd*Hd*Sd;   // second output, concatenated flat
  float* qbuf   = (float*)d_ws;                                      // [B][H] f32 = 128 KB
  unsigned short* Wrb = (unsigned short*)((char*)d_ws + 128*1024);   // [H][H] bf16 = 512 KB

  hipMemsetAsync(logits, 0, (size_t)Bd*Sd*sizeof(float), stream);
  prologue_kernel<<<192, 256, 0, stream>>>(Wr, Wrb, query, Wq, bq, qbuf);

  // grid: 64 batches x (16 n-tiles x 4 m-tiles), XCD-swizzled in-kernel
  fused_kernel<<<Bd*64, 256, 0, stream>>>(ref, Wrb, br, V, qbuf, out, logits);
}